// Round 17
// baseline (1086.180 us; speedup 1.0000x reference)
//
#include <hip/hip_runtime.h>
#include <hip/hip_bf16.h>
#include <math.h>

#define MINN 1e-15f
#define MAXN 0.996f  // (1 - 4e-3)/sqrt(c), c=1

#define KPAD 1472    // 23 * 64

typedef __attribute__((ext_vector_type(8))) short short8;
typedef __attribute__((ext_vector_type(4))) float f32x4;

__device__ __forceinline__ float artanhf_(float v){
  v = fminf(fmaxf(v, -0.9999999f), 0.9999999f);
  return 0.5f*(log1pf(v) - log1pf(-v));
}
__device__ __forceinline__ float grp8(float v){
  v += __shfl_xor(v,1,8); v += __shfl_xor(v,2,8); v += __shfl_xor(v,4,8); return v;
}
__device__ __forceinline__ float grp16w(float v){
  v += __shfl_xor(v,1,16); v += __shfl_xor(v,2,16);
  v += __shfl_xor(v,4,16); v += __shfl_xor(v,8,16); return v;
}
__device__ __forceinline__ unsigned short f2bf(float f){
  unsigned int u = __float_as_uint(f);
  unsigned int r = (u + 0x7fffu + ((u >> 16) & 1u)) >> 16;  // RNE
  return (unsigned short)r;
}
__device__ __forceinline__ float bf2f(unsigned short h){
  return __uint_as_float(((unsigned int)h) << 16);
}
__device__ __forceinline__ unsigned short f2bf_c(float f){
  __hip_bfloat16 b = __float2bfloat16(f);
  return *reinterpret_cast<unsigned short*>(&b);
}

typedef __attribute__((address_space(1))) const unsigned int gu32;
typedef __attribute__((address_space(3))) unsigned int su32;
__device__ __forceinline__ void gload_lds16(const void* g, void* s){
  __builtin_amdgcn_global_load_lds((gu32*)g, (su32*)s, 16, 0, 0);
}

// --- fused prep: w1 -> bf16 hi (RNE), counts zeroing, bias (block 0) ---
__global__ __launch_bounds__(256) void k_prep(const float* __restrict__ w1,
    const float* __restrict__ b1, const float* __restrict__ b2,
    unsigned short* __restrict__ w1hi,
    float* __restrict__ hb1, float* __restrict__ hb2, float* __restrict__ scal,
    int* __restrict__ counts, int N){
  int idx = blockIdx.x*256 + threadIdx.x;
  if (idx < 112*KPAD){
    int col = idx / KPAD, k = idx - col*KPAD;
    float v = (col < 100 && k < 1433) ? w1[(size_t)col*1433 + k] : 0.f;
    w1hi[idx] = f2bf(v);
  }
  if (idx < N) counts[idx] = 0;

  if (blockIdx.x == 0){
    __shared__ float red[128];
    int t = threadIdx.x;
    float v = (t < 100) ? b1[t] : 0.f;
    if (t < 128) red[t] = v*v;
    __syncthreads();
    for (int s=64;s;s>>=1){ if (t<s) red[t]+=red[t+s]; __syncthreads(); }
    float n2 = red[0]; __syncthreads();
    float n = fmaxf(sqrtf(n2), MINN);
    float s1 = tanhf(n)/n;
    float pn = fmaxf(tanhf(n), MINN);
    float t1 = pn > MAXN ? MAXN/pn : 1.f;
    float hv = s1*t1*v;
    if (t < 128) hb1[t] = (t<100) ? hv : 0.f;
    if (t < 128) red[t] = (t<100) ? hv*hv : 0.f;
    __syncthreads();
    for (int s=64;s;s>>=1){ if (t<s) red[t]+=red[t+s]; __syncthreads(); }
    if (t==0) scal[0] = red[0];
    __syncthreads();
    float v2 = (t < 64) ? b2[t] : 0.f;
    if (t < 128) red[t] = v2*v2;
    __syncthreads();
    for (int s=64;s;s>>=1){ if (t<s) red[t]+=red[t+s]; __syncthreads(); }
    float n2b = red[0]; __syncthreads();
    float nb = fmaxf(sqrtf(n2b), MINN);
    float s1b = tanhf(nb)/nb;
    float pnb = fmaxf(tanhf(nb), MINN);
    float t1b = pnb > MAXN ? MAXN/pnb : 1.f;
    float hvb = s1b*t1b*v2;
    if (t < 64) hb2[t] = hvb;
    if (t < 128) red[t] = (t<64) ? hvb*hvb : 0.f;
    __syncthreads();
    for (int s=64;s;s>>=1){ if (t<s) red[t]+=red[t+s]; __syncthreads(); }
    if (t==0) scal[1] = red[0];
  }
}

// --- MFMA lin1 + edge histogram. x split (hi+lo bf16), w plain bf16.
// 128 rows/block, 8 waves x 16 rows, BK=64 (23 iters), 512 threads, LDS 28KB.
// __launch_bounds__(512,8) pins VGPR<=64 -> 8 waves/SIMD -> whole grid co-resident
// (round-12 showed VGPR=68, one over the 64 occupancy quantum). No x register
// double-buffer (that was the +16 VGPRs); w prefetch via global_load_lds is free.
__global__ __launch_bounds__(512, 8) void k_lin1_mfma(
    const float* __restrict__ x, const unsigned short* __restrict__ w1hi,
    const float* __restrict__ hb1,
    const float* __restrict__ scal, unsigned short* __restrict__ xtan1, int N,
    const int* __restrict__ er, int* __restrict__ counts, int E)
{
  __shared__ alignas(16) char bsm[2*14*1024];   // 28 KB
  int tid = threadIdx.x;

  // --- edge histogram (overlaps with staging/memory stalls) ---
  {
    int gsz = gridDim.x * 512;
    for (int e = blockIdx.x*512 + tid; e < E; e += gsz)
      atomicAdd(&counts[er[e]], 1);
  }

  int w = tid >> 6, l = tid & 63;               // 8 waves
  int lr = l & 15, lg = l >> 4;
  int bm = blockIdx.x * 128;
  int row0 = bm + w*16;
  int r = row0 + lr;
  const float* xr = x + (size_t)min(r, N-1)*1433 + lg*8;
  float b1sq = scal[0];

  f32x4 acc[7];
  #pragma unroll
  for (int t=0;t<7;t++) acc[t] = (f32x4){0.f,0.f,0.f,0.f};
  float sq = 0.f;

  // chunk cc in [0,14): h = cc>=7 (k-half), t = cc-7h (col-tile).
  // lane l holds B[t*16+(l&15)][kbase + h*32 + (l>>4)*8 .. +8] at (buf*14+cc)*1024 + l*16.
  auto stage = [&](int buf, int kbase){
    #pragma unroll
    for (int c = 0; c < 2; ++c){
      int cc = w + 8*c;                          // 0..15
      if (cc < 14){
        int h = (cc >= 7) ? 1 : 0;
        int t = cc - h*7;
        const unsigned short* src = w1hi + (size_t)(t*16 + lr)*KPAD + kbase + h*32 + lg*8;
        gload_lds16(src, bsm + (buf*14 + cc)*1024);
      }
    }
  };
  auto xload = [&](float* d, int kbase){
    #pragma unroll
    for (int h = 0; h < 2; ++h){
      int kk = kbase + h*32;
      const float* p = xr + kk;
      if (kk + 32 <= 1433) {
        #pragma unroll
        for (int j=0;j<8;j++) d[h*8+j] = p[j];
      } else {
        #pragma unroll
        for (int j=0;j<8;j++){
          bool kv = (kk + lg*8 + j) < 1433;
          d[h*8+j] = kv ? p[j] : 0.f;
        }
      }
    }
  };

  stage(0, 0);
  __syncthreads();

  for (int kb = 0; kb < 23; ++kb) {
    int cur = kb & 1, nxt = cur ^ 1;
    int nk = (kb + 1) * 64;

    // w prefetch for next tile (async LDS, zero VGPR cost)
    if (kb + 1 < 23) stage(nxt, nk);

    // x load for CURRENT tile (latency hidden by 8 waves/SIMD TLP)
    float xc[16];
    xload(xc, kb*64);

    #pragma unroll
    for (int h = 0; h < 2; ++h){
      short8 ah, al;
      #pragma unroll
      for (int j=0;j<8;j++){
        float v = xc[h*8+j];
        sq = fmaf(v, v, sq);
        unsigned short hu = f2bf_c(v);
        ah[j] = (short)hu;
        float hf = bf2f(hu);
        al[j] = (short)f2bf_c(v - hf);
      }
      const char* base = bsm + (cur*14 + h*7)*1024 + (l << 4);
      short8 bh[7];
      #pragma unroll
      for (int t=0;t<7;t++)
        bh[t] = *reinterpret_cast<const short8*>(base + t*1024);
      #pragma unroll
      for (int t=0;t<7;t++){
        acc[t] = __builtin_amdgcn_mfma_f32_16x16x32_bf16(ah, bh[t], acc[t], 0,0,0);
        acc[t] = __builtin_amdgcn_mfma_f32_16x16x32_bf16(al, bh[t], acc[t], 0,0,0);
      }
    }

    __syncthreads();
  }

  sq += __shfl_xor(sq, 16); sq += __shfl_xor(sq, 32);

  float hbv[7];
  #pragma unroll
  for (int t=0;t<7;t++) hbv[t] = hb1[t*16 + lr];

  #pragma unroll
  for (int r4=0;r4<4;r4++){
    int rrow = 4*lg + r4;
    float v[7];
    #pragma unroll
    for (int t=0;t<7;t++) v[t] = acc[t][r4];
    float yn2 = 0.f, dotb = 0.f;
    #pragma unroll
    for (int t=0;t<7;t++){ yn2 += v[t]*v[t]; dotb += v[t]*hbv[t]; }
    yn2 = grp16w(yn2); dotb = grp16w(dotb);
    float xn2 = __shfl(sq, rrow);

    float un = fmaxf(sqrtf(xn2), MINN);
    float th = tanhf(un);
    float sE = th/un;
    float pn = fmaxf(th, MINN);
    float t1 = pn > MAXN ? MAXN/pn : 1.f;
    float gam = sE*t1;
    float xh = fmaxf(gam*un, MINN);
    float yn = sqrtf(yn2);
    float mxn = fmaxf(gam*yn, MINN);
    float rs = tanhf(mxn/xh*artanhf_(xh))/mxn;
    if (yn2 == 0.f) rs = 0.f;
    float rn = rs*gam*yn;
    float t2 = rn > MAXN ? MAXN/fmaxf(rn,MINN) : 1.f;
    float alpha = t2*rs*gam;
    float x2v = alpha*alpha*yn2;
    float xyv = alpha*dotb;
    float den = fmaxf(1.f + 2.f*xyv + x2v*b1sq, MINN);
    float A = (1.f + 2.f*xyv + b1sq)/den, B = (1.f - x2v)/den;
    float Aa = A*alpha;
    float on2 = 0.f;
    float o[7];
    #pragma unroll
    for (int t=0;t<7;t++){ o[t] = Aa*v[t] + B*hbv[t]; on2 += o[t]*o[t]; }
    on2 = grp16w(on2);
    float on = sqrtf(on2);
    float onc = fmaxf(on, MINN);
    float t3 = onc > MAXN ? MAXN/onc : 1.f;
    float pn3 = fmaxf(t3*on, MINN);
    float fs = artanhf_(pn3)/pn3 * t3;

    int grow = row0 + rrow;
    if (grow < N){
      #pragma unroll
      for (int t=0;t<7;t++){
        int c = t*16 + lr;
        if (c < 100) xtan1[(size_t)grow*100 + c] = f2bf(fs*o[t]);
      }
    }
  }
}

// ===================== CSR build (scan + scatter) =====================
__global__ __launch_bounds__(256) void k_scan1(const int* __restrict__ counts, int* __restrict__ row_start,
                                               int* __restrict__ blksum, int N){
  __shared__ int s[256];
  int t = threadIdx.x;
  int base = blockIdx.x*1024 + t*4;
  int v[4]; int sum = 0;
  #pragma unroll
  for (int i=0;i<4;i++){ v[i] = (base+i < N) ? counts[base+i] : 0; sum += v[i]; }
  s[t] = sum; __syncthreads();
  for (int off=1; off<256; off<<=1){
    int val = (t >= off) ? s[t-off] : 0;
    __syncthreads();
    s[t] += val;
    __syncthreads();
  }
  int run = (t > 0) ? s[t-1] : 0;
  #pragma unroll
  for (int i=0;i<4;i++){ if (base+i < N) row_start[base+i] = run; run += v[i]; }
  if (t == 255) blksum[blockIdx.x] = s[255];
}

__global__ __launch_bounds__(256) void k_scan3(int* __restrict__ row_start, const int* __restrict__ blksum,
                                               int* __restrict__ cursor, int N){
  __shared__ int pref;
  if (threadIdx.x == 0){
    int seg = blockIdx.x >> 2;
    int s = 0;
    for (int q = 0; q < seg; ++q) s += blksum[q];
    pref = s;
  }
  __syncthreads();
  int i = blockIdx.x*256 + threadIdx.x;
  if (i < N){ int v = row_start[i] + pref; row_start[i] = v; cursor[i] = v; }
}

__global__ __launch_bounds__(256) void k_scatter(const int* __restrict__ er, const int* __restrict__ ec,
    const float* __restrict__ ew, int* __restrict__ cursor,
    uint2* __restrict__ meta, int E){
  int e = blockIdx.x*256 + threadIdx.x;
  if (e < E){
    int r = er[e];
    int pos = atomicAdd(&cursor[r], 1);
    uint2 m;
    m.x = (unsigned int)ec[e];
    m.y = __float_as_uint(ew[e]);
    meta[pos] = m;
  }
}

// ===================== gather agg D=100: TWO rows per wave =====================
__global__ __launch_bounds__(256) void k_agg100(
    const unsigned short* __restrict__ xt, const int* __restrict__ row_start,
    const int* __restrict__ counts, const uint2* __restrict__ meta,
    float* __restrict__ sup, int N)
{
  int wv = threadIdx.x >> 6;
  int lane = threadIdx.x & 63;
  int pair = blockIdx.x*4 + wv;
  int rowA = pair*2;
  if (rowA >= N) return;
  int rowB = rowA + 1;
  bool hasB = rowB < N;
  int sl = lane & 31, half = lane >> 5;
  int startA = row_start[rowA], cntA = counts[rowA];
  int startB = hasB ? row_start[rowB] : 0;
  int cntB   = hasB ? counts[rowB] : 0;
  bool act = lane < 50;
  float a0=0.f, a1=0.f, b0=0.f, b1=0.f;
  int cmax = max(cntA, cntB);

  for (int j = 0; j < cmax; j += 32) {
    int cc = 0; float wt = 0.f;
    int myStart = half ? startB : startA;
    int myCnt   = half ? cntB   : cntA;
    if (j + sl < myCnt){ uint2 m = meta[myStart + j + sl]; cc = (int)m.x; wt = __uint_as_float(m.y); }
    int limA = min(32, cntA - j);
    int limB = min(32, cntB - j);
    int limJ = min(limA, limB);
    int k = 0;
    for (; k + 4 <= limJ; k += 4) {
      const unsigned int *pa0,*pa1,*pa2,*pa3,*pb0,*pb1,*pb2,*pb3;
      float wa0,wa1,wa2,wa3,wb0,wb1,wb2,wb3;
      pa0 = reinterpret_cast<const unsigned int*>(xt + (size_t)__shfl(cc,k+0)*100); wa0 = __shfl(wt,k+0);
      pa1 = reinterpret_cast<const unsigned int*>(xt + (size_t)__shfl(cc,k+1)*100); wa1 = __shfl(wt,k+1);
      pa2 = reinterpret_cast<const unsigned int*>(xt + (size_t)__shfl(cc,k+2)*100); wa2 = __shfl(wt,k+2);
      pa3 = reinterpret_cast<const unsigned int*>(xt + (size_t)__shfl(cc,k+3)*100); wa3 = __shfl(wt,k+3);
      pb0 = reinterpret_cast<const unsigned int*>(xt + (size_t)__shfl(cc,32+k+0)*100); wb0 = __shfl(wt,32+k+0);
      pb1 = reinterpret_cast<const unsigned int*>(xt + (size_t)__shfl(cc,32+k+1)*100); wb1 = __shfl(wt,32+k+1);
      pb2 = reinterpret_cast<const unsigned int*>(xt + (size_t)__shfl(cc,32+k+2)*100); wb2 = __shfl(wt,32+k+2);
      pb3 = reinterpret_cast<const unsigned int*>(xt + (size_t)__shfl(cc,32+k+3)*100); wb3 = __shfl(wt,32+k+3);
      if (act){
        unsigned int uA0=pa0[lane],uA1=pa1[lane],uA2=pa2[lane],uA3=pa3[lane];
        unsigned int uB0=pb0[lane],uB1=pb1[lane],uB2=pb2[lane],uB3=pb3[lane];
        a0 += wa0*bf2f((unsigned short)uA0); a1 += wa0*bf2f((unsigned short)(uA0>>16));
        a0 += wa1*bf2f((unsigned short)uA1); a1 += wa1*bf2f((unsigned short)(uA1>>16));
        a0 += wa2*bf2f((unsigned short)uA2); a1 += wa2*bf2f((unsigned short)(uA2>>16));
        a0 += wa3*bf2f((unsigned short)uA3); a1 += wa3*bf2f((unsigned short)(uA3>>16));
        b0 += wb0*bf2f((unsigned short)uB0); b1 += wb0*bf2f((unsigned short)(uB0>>16));
        b0 += wb1*bf2f((unsigned short)uB1); b1 += wb1*bf2f((unsigned short)(uB1>>16));
        b0 += wb2*bf2f((unsigned short)uB2); b1 += wb2*bf2f((unsigned short)(uB2>>16));
        b0 += wb3*bf2f((unsigned short)uB3); b1 += wb3*bf2f((unsigned short)(uB3>>16));
      }
    }
    int kA = k, kB = k;
    for (; kA < limA; ++kA) {
      int col = __shfl(cc, kA);
      float w_ = __shfl(wt, kA);
      if (act){
        unsigned int u = reinterpret_cast<const unsigned int*>(xt + (size_t)col*100)[lane];
        a0 += w_*bf2f((unsigned short)u);
        a1 += w_*bf2f((unsigned short)(u>>16));
      }
    }
    for (; kB < limB; ++kB) {
      int col = __shfl(cc, 32+kB);
      float w_ = __shfl(wt, 32+kB);
      if (act){
        unsigned int u = reinterpret_cast<const unsigned int*>(xt + (size_t)col*100)[lane];
        b0 += w_*bf2f((unsigned short)u);
        b1 += w_*bf2f((unsigned short)(u>>16));
      }
    }
  }
  if (act){
    float2* dstA = reinterpret_cast<float2*>(sup + (size_t)rowA*100);
    dstA[lane] = make_float2(a0, a1);
    if (hasB){
      float2* dstB = reinterpret_cast<float2*>(sup + (size_t)rowB*100);
      dstB[lane] = make_float2(b0, b1);
    }
  }
}

// ===================== gather agg D=64: half-split, one row per 32-lane half =====================
__global__ __launch_bounds__(256) void k_agg64(
    const unsigned short* __restrict__ xt, const int* __restrict__ row_start,
    const int* __restrict__ counts, const uint2* __restrict__ meta,
    float* __restrict__ sup, int N)
{
  int wv = threadIdx.x >> 6;
  int lane = threadIdx.x & 63;
  int pair = blockIdx.x*4 + wv;
  int rowA = pair*2;
  if (rowA >= N) return;
  int rowB = rowA + 1;
  bool hasB = rowB < N;
  int half = lane >> 5, sl = lane & 31;
  int myRow = half ? rowB : rowA;
  bool live = (half == 0) || hasB;
  int myStart = 0, myCnt = 0;
  if (live){ myStart = row_start[myRow]; myCnt = counts[myRow]; }
  float a0 = 0.f, a1 = 0.f;

  for (int j = 0; j < myCnt; j += 32) {
    int cc = 0; float wt = 0.f;
    if (j + sl < myCnt){ uint2 m = meta[myStart + j + sl]; cc = (int)m.x; wt = __uint_as_float(m.y); }
    int lim = min(32, myCnt - j);
    int hb = half*32;
    int k = 0;
    for (; k + 8 <= lim; k += 8) {
      const unsigned int *p0,*p1,*p2,*p3,*p4,*p5,*p6,*p7;
      float w0,w1,w2,w3,w4,w5,w6,w7;
      p0 = reinterpret_cast<const unsigned int*>(xt + (size_t)__shfl(cc,hb+k+0)*64); w0 = __shfl(wt,hb+k+0);
      p1 = reinterpret_cast<const unsigned int*>(xt + (size_t)__shfl(cc,hb+k+1)*64); w1 = __shfl(wt,hb+k+1);
      p2 = reinterpret_cast<const unsigned int*>(xt + (size_t)__shfl(cc,hb+k+2)*64); w2 = __shfl(wt,hb+k+2);
      p3 = reinterpret_cast<const unsigned int*>(xt + (size_t)__shfl(cc,hb+k+3)*64); w3 = __shfl(wt,hb+k+3);
      p4 = reinterpret_cast<const unsigned int*>(xt + (size_t)__shfl(cc,hb+k+4)*64); w4 = __shfl(wt,hb+k+4);
      p5 = reinterpret_cast<const unsigned int*>(xt + (size_t)__shfl(cc,hb+k+5)*64); w5 = __shfl(wt,hb+k+5);
      p6 = reinterpret_cast<const unsigned int*>(xt + (size_t)__shfl(cc,hb+k+6)*64); w6 = __shfl(wt,hb+k+6);
      p7 = reinterpret_cast<const unsigned int*>(xt + (size_t)__shfl(cc,hb+k+7)*64); w7 = __shfl(wt,hb+k+7);
      unsigned int u0=p0[sl],u1=p1[sl],u2=p2[sl],u3=p3[sl];
      unsigned int u4=p4[sl],u5=p5[sl],u6=p6[sl],u7=p7[sl];
      a0 += w0*bf2f((unsigned short)u0); a1 += w0*bf2f((unsigned short)(u0>>16));
      a0 += w1*bf2f((unsigned short)u1); a1 += w1*bf2f((unsigned short)(u1>>16));
      a0 += w2*bf2f((unsigned short)u2); a1 += w2*bf2f((unsigned short)(u2>>16));
      a0 += w3*bf2f((unsigned short)u3); a1 += w3*bf2f((unsigned short)(u3>>16));
      a0 += w4*bf2f((unsigned short)u4); a1 += w4*bf2f((unsigned short)(u4>>16));
      a0 += w5*bf2f((unsigned short)u5); a1 += w5*bf2f((unsigned short)(u5>>16));
      a0 += w6*bf2f((unsigned short)u6); a1 += w6*bf2f((unsigned short)(u6>>16));
      a0 += w7*bf2f((unsigned short)u7); a1 += w7*bf2f((unsigned short)(u7>>16));
    }
    for (; k < lim; ++k) {
      int col = __shfl(cc, hb+k);
      float w_ = __shfl(wt, hb+k);
      unsigned int u = reinterpret_cast<const unsigned int*>(xt + (size_t)col*64)[sl];
      a0 += w_*bf2f((unsigned short)u);
      a1 += w_*bf2f((unsigned short)(u>>16));
    }
  }
  if (live){
    float2* dst = reinterpret_cast<float2*>(sup + (size_t)myRow*64);
    dst[sl] = make_float2(a0, a1);
  }
}

// --- fused: proj(expmap0(support1)) -> hyp_act -> mobius_matvec(w2) -> +bias2 -> proj -> logmap0 ---
__global__ __launch_bounds__(256) void k_layer2(
    const float* __restrict__ sup, const float* __restrict__ w2,
    const float* __restrict__ hb2, const float* __restrict__ scal,
    unsigned short* __restrict__ xtan2, int N)
{
  __shared__ alignas(16) float w2s[64][100];
  __shared__ float xts[32][105];
  __shared__ float hbs[64];
  int tid = threadIdx.x;
  for (int i = tid; i < 1600; i += 256)
    reinterpret_cast<float4*>(&w2s[0][0])[i] = reinterpret_cast<const float4*>(w2)[i];
  if (tid < 64) hbs[tid] = hb2[tid];
  float b2sq = scal[1];
  __syncthreads();
  int rr = tid >> 3, g = tid & 7;
  int grow = blockIdx.x*32 + rr;
  bool valid = grow < N;
  float sv[13]; float sn2 = 0.f;
  #pragma unroll
  for (int m=0;m<13;m++){
    int j = g + 8*m;
    float v = (valid && j < 100) ? sup[(size_t)grow*100 + j] : 0.f;
    sv[m] = v; sn2 += v*v;
  }
  sn2 = grp8(sn2);
  float snn = fmaxf(sqrtf(sn2), MINN);
  float e1 = tanhf(snn)/snn;
  float pnA = fmaxf(tanhf(snn), MINN);
  float t1 = pnA > MAXN ? MAXN/pnA : 1.f;
  float phi = e1*t1;
  float hn = fmaxf(phi*snn, MINN);
  float lam = artanhf_(hn)/hn;
  float xn2 = 0.f;
  #pragma unroll
  for (int m=0;m<13;m++){
    int j = g + 8*m;
    if (j < 100){ float v = fmaxf(lam*phi*sv[m], 0.f); xts[rr][j] = v; xn2 += v*v; }
  }
  xn2 = grp8(xn2);
  float xn = fmaxf(sqrtf(xn2), MINN);
  float e2 = tanhf(xn)/xn;
  float pnB = fmaxf(tanhf(xn), MINN);
  float t2 = pnB > MAXN ? MAXN/pnB : 1.f;
  float psi = e2*t2;
  __syncthreads();
  float z[8] = {};
  for (int j=0;j<100;j++){
    float xv = xts[rr][j];
    #pragma unroll
    for (int m=0;m<8;m++) z[m] += xv * w2s[g+8*m][j];
  }
  float zn2 = 0.f, dz = 0.f;
  #pragma unroll
  for (int m=0;m<8;m++){ zn2 += z[m]*z[m]; dz += z[m]*hbs[g+8*m]; }
  zn2 = grp8(zn2); dz = grp8(dz);
  float xnh = fmaxf(psi*xn, MINN);
  float zn = sqrtf(zn2);
  float mxn = fmaxf(psi*zn, MINN);
  float rs = tanhf(mxn/xnh*artanhf_(xnh))/mxn;
  if (zn2 == 0.f) rs = 0.f;
  float rn = rs*psi*zn;
  float t3 = rn > MAXN ? MAXN/fmaxf(rn,MINN) : 1.f;
  float alpha = t3*rs*psi;
  float x2 = alpha*alpha*zn2;
  float xy = alpha*dz;
  float den = fmaxf(1.f + 2.f*xy + x2*b2sq, MINN);
  float A = (1.f + 2.f*xy + b2sq)/den, B = (1.f - x2)/den;
  float Aa = A*alpha;
  float ov[8]; float on2 = 0.f;
  #pragma unroll
  for (int m=0;m<8;m++){ ov[m] = Aa*z[m] + B*hbs[g+8*m]; on2 += ov[m]*ov[m]; }
  on2 = grp8(on2);
  float on = sqrtf(on2);
  float onc = fmaxf(on, MINN);
  float t4 = onc > MAXN ? MAXN/onc : 1.f;
  float pn4 = fmaxf(t4*on, MINN);
  float fs = artanhf_(pn4)/pn4 * t4;
  if (valid)
    #pragma unroll
    for (int m=0;m<8;m++) xtan2[(size_t)grow*64 + g + 8*m] = f2bf(fs*ov[m]);
}

// --- fused: proj(expmap0(support2)) -> hyp_act -> logmap0 -> linear(7) + relu -> log_softmax ---
__global__ __launch_bounds__(256) void k_decode(
    const float* __restrict__ sup2, const float* __restrict__ lw,
    const float* __restrict__ lb, float* __restrict__ out, int N)
{
  __shared__ float lws[7][64];
  __shared__ float lbs[7];
  int tid = threadIdx.x;
  for (int i = tid; i < 448; i += 256) lws[i>>6][i&63] = lw[i];
  if (tid < 7) lbs[tid] = lb[tid];
  __syncthreads();
  int rr = tid >> 3, g = tid & 7;
  int grow = blockIdx.x*32 + rr;
  bool valid = grow < N;
  float sv[8]; float sn2 = 0.f;
  #pragma unroll
  for (int m=0;m<8;m++){
    int j = g + 8*m;
    float v = valid ? sup2[(size_t)grow*64 + j] : 0.f;
    sv[m] = v; sn2 += v*v;
  }
  sn2 = grp8(sn2);
  float snn = fmaxf(sqrtf(sn2), MINN);
  float e1 = tanhf(snn)/snn;
  float pnA = fmaxf(tanhf(snn), MINN);
  float t1 = pnA > MAXN ? MAXN/pnA : 1.f;
  float phi = e1*t1;
  float hn = fmaxf(phi*snn, MINN);
  float lam = artanhf_(hn)/hn;
  float xt[8]; float xn2 = 0.f;
  #pragma unroll
  for (int m=0;m<8;m++){ xt[m] = fmaxf(lam*phi*sv[m], 0.f); xn2 += xt[m]*xt[m]; }
  xn2 = grp8(xn2);
  float xn = fmaxf(sqrtf(xn2), MINN);
  float e2 = tanhf(xn)/xn;
  float pnB = fmaxf(tanhf(xn), MINN);
  float t2 = pnB > MAXN ? MAXN/pnB : 1.f;
  float psi = e2*t2;
  float tn = fmaxf(psi*xn, MINN);
  float lam2 = artanhf_(tn)/tn;
  float tc = lam2*psi;
  float lg[7];
  #pragma unroll
  for (int k=0;k<7;k++){
    float p = 0.f;
    #pragma unroll
    for (int m=0;m<8;m++) p += xt[m]*lws[k][g+8*m];
    p = grp8(p) * tc;
    lg[k] = fmaxf(p + lbs[k], 0.f);
  }
  float mx = lg[0];
  #pragma unroll
  for (int k=1;k<7;k++) mx = fmaxf(mx, lg[k]);
  float se = 0.f;
  #pragma unroll
  for (int k=0;k<7;k++) se += expf(lg[k]-mx);
  float lse = logf(se);
  if (valid && g < 7) out[(size_t)grow*7 + g] = lg[g] - mx - lse;
}

extern "C" void kernel_launch(void* const* d_in, const int* in_sizes, int n_in,
                              void* d_out, int out_size, void* d_ws, size_t ws_size,
                              hipStream_t stream)
{
  const float* x  = (const float*)d_in[0];
  const int*   er = (const int*)  d_in[1];
  const int*   ec = (const int*)  d_in[2];
  const float* ew = (const float*)d_in[3];
  const float* w1 = (const float*)d_in[4];
  const float* b1 = (const float*)d_in[5];
  const float* w2 = (const float*)d_in[6];
  const float* b2 = (const float*)d_in[7];
  const float* lw = (const float*)d_in[8];
  const float* lb = (const float*)d_in[9];
  float* out = (float*)d_out;
  int N = in_sizes[0] / 1433;
  int E = in_sizes[1];

  float* W = (float*)d_ws;
  float* hb1  = W;                                      // 128
  float* hb2  = W + 128;                                // 64
  float* scal = W + 192;                                // 2
  unsigned short* w1hi = (unsigned short*)(W + 256);    // 112*KPAD ushorts = 82432 floats
  uint2* meta = (uint2*)(W + 82688);                    // E * 8B
  int*   counts    = (int*)(W + 82688 + 2*(size_t)E);   // N
  int*   row_start = counts + N;                        // N
  int*   cursor    = row_start + N;                     // N
  int*   blksum    = cursor + N;                        // 128
  unsigned short* xtanb = (unsigned short*)(blksum + 128);  // N*100 ushorts (xtan1 / xtan2)
  float* sup = (float*)(xtanb + (size_t)N*100);         // N*100 floats (sup1 / sup2)

  int nblk_scan = (N + 1023) / 1024;
  int nb128 = (N + 127)/128;
  int npair = (N + 1)/2;
  int nbg = (npair + 3)/4;
  int nb32 = (N + 31)/32;

  k_prep<<<(112*KPAD + 255)/256, 256, 0, stream>>>(w1, b1, b2, w1hi, hb1, hb2, scal, counts, N);
  k_lin1_mfma<<<nb128, 512, 0, stream>>>(x, w1hi, hb1, scal, xtanb, N, er, counts, E);
  k_scan1<<<nblk_scan, 256, 0, stream>>>(counts, row_start, blksum, N);
  k_scan3<<<(N + 255)/256, 256, 0, stream>>>(row_start, blksum, cursor, N);
  k_scatter<<<(E + 255)/256, 256, 0, stream>>>(er, ec, ew, cursor, meta, E);
  k_agg100<<<nbg, 256, 0, stream>>>(xtanb, row_start, counts, meta, sup, N);
  k_layer2<<<nb32, 256, 0, stream>>>(sup, w2, hb2, scal, xtanb, N);
  k_agg64<<<nbg, 256, 0, stream>>>(xtanb, row_start, counts, meta, sup, N);
  k_decode<<<nb32, 256, 0, stream>>>(sup, lw, lb, out, N);
}

// Round 18
// 562.979 us; speedup vs baseline: 1.9293x; 1.9293x over previous
//
#include <hip/hip_runtime.h>
#include <hip/hip_bf16.h>
#include <math.h>

#define MINN 1e-15f
#define MAXN 0.996f  // (1 - 4e-3)/sqrt(c), c=1

#define KPAD 1472    // 23 * 64

typedef __attribute__((ext_vector_type(8))) short short8;
typedef __attribute__((ext_vector_type(4))) float f32x4;

__device__ __forceinline__ float artanhf_(float v){
  v = fminf(fmaxf(v, -0.9999999f), 0.9999999f);
  return 0.5f*(log1pf(v) - log1pf(-v));
}
__device__ __forceinline__ float grp8(float v){
  v += __shfl_xor(v,1,8); v += __shfl_xor(v,2,8); v += __shfl_xor(v,4,8); return v;
}
__device__ __forceinline__ float grp16w(float v){
  v += __shfl_xor(v,1,16); v += __shfl_xor(v,2,16);
  v += __shfl_xor(v,4,16); v += __shfl_xor(v,8,16); return v;
}
__device__ __forceinline__ unsigned short f2bf(float f){
  unsigned int u = __float_as_uint(f);
  unsigned int r = (u + 0x7fffu + ((u >> 16) & 1u)) >> 16;  // RNE
  return (unsigned short)r;
}
__device__ __forceinline__ float bf2f(unsigned short h){
  return __uint_as_float(((unsigned int)h) << 16);
}
__device__ __forceinline__ unsigned short f2bf_c(float f){
  __hip_bfloat16 b = __float2bfloat16(f);
  return *reinterpret_cast<unsigned short*>(&b);
}

typedef __attribute__((address_space(1))) const unsigned int gu32;
typedef __attribute__((address_space(3))) unsigned int su32;
__device__ __forceinline__ void gload_lds16(const void* g, void* s){
  __builtin_amdgcn_global_load_lds((gu32*)g, (su32*)s, 16, 0, 0);
}

// --- fused prep: w1 -> bf16 hi (RNE), counts zeroing, bias (block 0) ---
__global__ __launch_bounds__(256) void k_prep(const float* __restrict__ w1,
    const float* __restrict__ b1, const float* __restrict__ b2,
    unsigned short* __restrict__ w1hi,
    float* __restrict__ hb1, float* __restrict__ hb2, float* __restrict__ scal,
    int* __restrict__ counts, int N){
  int idx = blockIdx.x*256 + threadIdx.x;
  if (idx < 112*KPAD){
    int col = idx / KPAD, k = idx - col*KPAD;
    float v = (col < 100 && k < 1433) ? w1[(size_t)col*1433 + k] : 0.f;
    w1hi[idx] = f2bf(v);
  }
  if (idx < N) counts[idx] = 0;

  if (blockIdx.x == 0){
    __shared__ float red[128];
    int t = threadIdx.x;
    float v = (t < 100) ? b1[t] : 0.f;
    if (t < 128) red[t] = v*v;
    __syncthreads();
    for (int s=64;s;s>>=1){ if (t<s) red[t]+=red[t+s]; __syncthreads(); }
    float n2 = red[0]; __syncthreads();
    float n = fmaxf(sqrtf(n2), MINN);
    float s1 = tanhf(n)/n;
    float pn = fmaxf(tanhf(n), MINN);
    float t1 = pn > MAXN ? MAXN/pn : 1.f;
    float hv = s1*t1*v;
    if (t < 128) hb1[t] = (t<100) ? hv : 0.f;
    if (t < 128) red[t] = (t<100) ? hv*hv : 0.f;
    __syncthreads();
    for (int s=64;s;s>>=1){ if (t<s) red[t]+=red[t+s]; __syncthreads(); }
    if (t==0) scal[0] = red[0];
    __syncthreads();
    float v2 = (t < 64) ? b2[t] : 0.f;
    if (t < 128) red[t] = v2*v2;
    __syncthreads();
    for (int s=64;s;s>>=1){ if (t<s) red[t]+=red[t+s]; __syncthreads(); }
    float n2b = red[0]; __syncthreads();
    float nb = fmaxf(sqrtf(n2b), MINN);
    float s1b = tanhf(nb)/nb;
    float pnb = fmaxf(tanhf(nb), MINN);
    float t1b = pnb > MAXN ? MAXN/pnb : 1.f;
    float hvb = s1b*t1b*v2;
    if (t < 64) hb2[t] = hvb;
    if (t < 128) red[t] = (t<64) ? hvb*hvb : 0.f;
    __syncthreads();
    for (int s=64;s;s>>=1){ if (t<s) red[t]+=red[t+s]; __syncthreads(); }
    if (t==0) scal[1] = red[0];
  }
}

// --- MFMA lin1 + edge histogram. x split (hi+lo bf16), w plain bf16 (2 MFMA/tile).
// 128 rows/block, 8 waves x 16 rows, BK=64, 512 threads, LDS 28KB.
// Round-14 best structure: natural VGPR (~68), x register double-buffer.
// Lesson (r17): pinning waves/EU below the register footprint -> scratch spills
// (VGPR 68->32, FETCH 299MB->1.03GB, 3x slower). Never bound below need.
__global__ __launch_bounds__(512) void k_lin1_mfma(
    const float* __restrict__ x, const unsigned short* __restrict__ w1hi,
    const float* __restrict__ hb1,
    const float* __restrict__ scal, unsigned short* __restrict__ xtan1, int N,
    const int* __restrict__ er, int* __restrict__ counts, int E)
{
  __shared__ alignas(16) char bsm[2*14*1024];   // 28 KB
  int tid = threadIdx.x;

  // --- edge histogram (overlaps with staging/memory stalls) ---
  {
    int gsz = gridDim.x * 512;
    for (int e = blockIdx.x*512 + tid; e < E; e += gsz)
      atomicAdd(&counts[er[e]], 1);
  }

  int w = tid >> 6, l = tid & 63;               // 8 waves
  int lr = l & 15, lg = l >> 4;
  int bm = blockIdx.x * 128;
  int row0 = bm + w*16;
  int r = row0 + lr;
  const float* xr = x + (size_t)min(r, N-1)*1433 + lg*8;
  float b1sq = scal[0];

  f32x4 acc[7];
  #pragma unroll
  for (int t=0;t<7;t++) acc[t] = (f32x4){0.f,0.f,0.f,0.f};
  float sq = 0.f;

  auto stage = [&](int buf, int kbase){
    #pragma unroll
    for (int c = 0; c < 2; ++c){
      int cc = w + 8*c;                          // 0..15
      if (cc < 14){
        int h = (cc >= 7) ? 1 : 0;
        int t = cc - h*7;
        const unsigned short* src = w1hi + (size_t)(t*16 + lr)*KPAD + kbase + h*32 + lg*8;
        gload_lds16(src, bsm + (buf*14 + cc)*1024);
      }
    }
  };
  auto xload = [&](float* d, int kbase){
    #pragma unroll
    for (int h = 0; h < 2; ++h){
      int kk = kbase + h*32;
      const float* p = xr + kk;
      if (kk + 32 <= 1433) {
        #pragma unroll
        for (int j=0;j<8;j++) d[h*8+j] = p[j];
      } else {
        #pragma unroll
        for (int j=0;j<8;j++){
          bool kv = (kk + lg*8 + j) < 1433;
          d[h*8+j] = kv ? p[j] : 0.f;
        }
      }
    }
  };

  float xa[16];
  xload(xa, 0);
  stage(0, 0);
  __syncthreads();

  for (int kb = 0; kb < 23; ++kb) {
    int cur = kb & 1, nxt = cur ^ 1;
    int nk = (kb + 1) * 64;

    float xb[16];
    if (kb + 1 < 23){
      xload(xb, nk);      // long-latency x prefetch issued first
      stage(nxt, nk);
    } else {
      #pragma unroll
      for (int j=0;j<16;j++) xb[j] = 0.f;
    }

    #pragma unroll
    for (int h = 0; h < 2; ++h){
      short8 ah, al;
      #pragma unroll
      for (int j=0;j<8;j++){
        float v = xa[h*8+j];
        sq = fmaf(v, v, sq);
        unsigned short hu = f2bf_c(v);
        ah[j] = (short)hu;
        float hf = bf2f(hu);
        al[j] = (short)f2bf_c(v - hf);
      }
      const char* base = bsm + (cur*14 + h*7)*1024 + (l << 4);
      short8 bh[7];
      #pragma unroll
      for (int t=0;t<7;t++)
        bh[t] = *reinterpret_cast<const short8*>(base + t*1024);
      #pragma unroll
      for (int t=0;t<7;t++){
        acc[t] = __builtin_amdgcn_mfma_f32_16x16x32_bf16(ah, bh[t], acc[t], 0,0,0);
        acc[t] = __builtin_amdgcn_mfma_f32_16x16x32_bf16(al, bh[t], acc[t], 0,0,0);
      }
    }
    #pragma unroll
    for (int j=0;j<16;j++) xa[j] = xb[j];

    __syncthreads();
  }

  sq += __shfl_xor(sq, 16); sq += __shfl_xor(sq, 32);

  float hbv[7];
  #pragma unroll
  for (int t=0;t<7;t++) hbv[t] = hb1[t*16 + lr];

  #pragma unroll
  for (int r4=0;r4<4;r4++){
    int rrow = 4*lg + r4;
    float v[7];
    #pragma unroll
    for (int t=0;t<7;t++) v[t] = acc[t][r4];
    float yn2 = 0.f, dotb = 0.f;
    #pragma unroll
    for (int t=0;t<7;t++){ yn2 += v[t]*v[t]; dotb += v[t]*hbv[t]; }
    yn2 = grp16w(yn2); dotb = grp16w(dotb);
    float xn2 = __shfl(sq, rrow);

    float un = fmaxf(sqrtf(xn2), MINN);
    float th = tanhf(un);
    float sE = th/un;
    float pn = fmaxf(th, MINN);
    float t1 = pn > MAXN ? MAXN/pn : 1.f;
    float gam = sE*t1;
    float xh = fmaxf(gam*un, MINN);
    float yn = sqrtf(yn2);
    float mxn = fmaxf(gam*yn, MINN);
    float rs = tanhf(mxn/xh*artanhf_(xh))/mxn;
    if (yn2 == 0.f) rs = 0.f;
    float rn = rs*gam*yn;
    float t2 = rn > MAXN ? MAXN/fmaxf(rn,MINN) : 1.f;
    float alpha = t2*rs*gam;
    float x2v = alpha*alpha*yn2;
    float xyv = alpha*dotb;
    float den = fmaxf(1.f + 2.f*xyv + x2v*b1sq, MINN);
    float A = (1.f + 2.f*xyv + b1sq)/den, B = (1.f - x2v)/den;
    float Aa = A*alpha;
    float on2 = 0.f;
    float o[7];
    #pragma unroll
    for (int t=0;t<7;t++){ o[t] = Aa*v[t] + B*hbv[t]; on2 += o[t]*o[t]; }
    on2 = grp16w(on2);
    float on = sqrtf(on2);
    float onc = fmaxf(on, MINN);
    float t3 = onc > MAXN ? MAXN/onc : 1.f;
    float pn3 = fmaxf(t3*on, MINN);
    float fs = artanhf_(pn3)/pn3 * t3;

    int grow = row0 + rrow;
    if (grow < N){
      #pragma unroll
      for (int t=0;t<7;t++){
        int c = t*16 + lr;
        if (c < 100) xtan1[(size_t)grow*100 + c] = f2bf(fs*o[t]);
      }
    }
  }
}

// ===================== CSR build (scan + scatter) =====================
__global__ __launch_bounds__(256) void k_scan1(const int* __restrict__ counts, int* __restrict__ row_start,
                                               int* __restrict__ blksum, int N){
  __shared__ int s[256];
  int t = threadIdx.x;
  int base = blockIdx.x*1024 + t*4;
  int v[4]; int sum = 0;
  #pragma unroll
  for (int i=0;i<4;i++){ v[i] = (base+i < N) ? counts[base+i] : 0; sum += v[i]; }
  s[t] = sum; __syncthreads();
  for (int off=1; off<256; off<<=1){
    int val = (t >= off) ? s[t-off] : 0;
    __syncthreads();
    s[t] += val;
    __syncthreads();
  }
  int run = (t > 0) ? s[t-1] : 0;
  #pragma unroll
  for (int i=0;i<4;i++){ if (base+i < N) row_start[base+i] = run; run += v[i]; }
  if (t == 255) blksum[blockIdx.x] = s[255];
}

__global__ __launch_bounds__(256) void k_scan3(int* __restrict__ row_start, const int* __restrict__ blksum,
                                               int* __restrict__ cursor, int N){
  __shared__ int pref;
  if (threadIdx.x == 0){
    int seg = blockIdx.x >> 2;
    int s = 0;
    for (int q = 0; q < seg; ++q) s += blksum[q];
    pref = s;
  }
  __syncthreads();
  int i = blockIdx.x*256 + threadIdx.x;
  if (i < N){ int v = row_start[i] + pref; row_start[i] = v; cursor[i] = v; }
}

__global__ __launch_bounds__(256) void k_scatter(const int* __restrict__ er, const int* __restrict__ ec,
    const float* __restrict__ ew, int* __restrict__ cursor,
    uint2* __restrict__ meta, int E){
  int e = blockIdx.x*256 + threadIdx.x;
  if (e < E){
    int r = er[e];
    int pos = atomicAdd(&cursor[r], 1);
    uint2 m;
    m.x = (unsigned int)ec[e];
    m.y = __float_as_uint(ew[e]);
    meta[pos] = m;
  }
}

// ===================== gather agg D=100: TWO rows per wave =====================
__global__ __launch_bounds__(256) void k_agg100(
    const unsigned short* __restrict__ xt, const int* __restrict__ row_start,
    const int* __restrict__ counts, const uint2* __restrict__ meta,
    float* __restrict__ sup, int N)
{
  int wv = threadIdx.x >> 6;
  int lane = threadIdx.x & 63;
  int pair = blockIdx.x*4 + wv;
  int rowA = pair*2;
  if (rowA >= N) return;
  int rowB = rowA + 1;
  bool hasB = rowB < N;
  int sl = lane & 31, half = lane >> 5;
  int startA = row_start[rowA], cntA = counts[rowA];
  int startB = hasB ? row_start[rowB] : 0;
  int cntB   = hasB ? counts[rowB] : 0;
  bool act = lane < 50;
  float a0=0.f, a1=0.f, b0=0.f, b1=0.f;
  int cmax = max(cntA, cntB);

  for (int j = 0; j < cmax; j += 32) {
    int cc = 0; float wt = 0.f;
    int myStart = half ? startB : startA;
    int myCnt   = half ? cntB   : cntA;
    if (j + sl < myCnt){ uint2 m = meta[myStart + j + sl]; cc = (int)m.x; wt = __uint_as_float(m.y); }
    int limA = min(32, cntA - j);
    int limB = min(32, cntB - j);
    int limJ = min(limA, limB);
    int k = 0;
    for (; k + 4 <= limJ; k += 4) {
      const unsigned int *pa0,*pa1,*pa2,*pa3,*pb0,*pb1,*pb2,*pb3;
      float wa0,wa1,wa2,wa3,wb0,wb1,wb2,wb3;
      pa0 = reinterpret_cast<const unsigned int*>(xt + (size_t)__shfl(cc,k+0)*100); wa0 = __shfl(wt,k+0);
      pa1 = reinterpret_cast<const unsigned int*>(xt + (size_t)__shfl(cc,k+1)*100); wa1 = __shfl(wt,k+1);
      pa2 = reinterpret_cast<const unsigned int*>(xt + (size_t)__shfl(cc,k+2)*100); wa2 = __shfl(wt,k+2);
      pa3 = reinterpret_cast<const unsigned int*>(xt + (size_t)__shfl(cc,k+3)*100); wa3 = __shfl(wt,k+3);
      pb0 = reinterpret_cast<const unsigned int*>(xt + (size_t)__shfl(cc,32+k+0)*100); wb0 = __shfl(wt,32+k+0);
      pb1 = reinterpret_cast<const unsigned int*>(xt + (size_t)__shfl(cc,32+k+1)*100); wb1 = __shfl(wt,32+k+1);
      pb2 = reinterpret_cast<const unsigned int*>(xt + (size_t)__shfl(cc,32+k+2)*100); wb2 = __shfl(wt,32+k+2);
      pb3 = reinterpret_cast<const unsigned int*>(xt + (size_t)__shfl(cc,32+k+3)*100); wb3 = __shfl(wt,32+k+3);
      if (act){
        unsigned int uA0=pa0[lane],uA1=pa1[lane],uA2=pa2[lane],uA3=pa3[lane];
        unsigned int uB0=pb0[lane],uB1=pb1[lane],uB2=pb2[lane],uB3=pb3[lane];
        a0 += wa0*bf2f((unsigned short)uA0); a1 += wa0*bf2f((unsigned short)(uA0>>16));
        a0 += wa1*bf2f((unsigned short)uA1); a1 += wa1*bf2f((unsigned short)(uA1>>16));
        a0 += wa2*bf2f((unsigned short)uA2); a1 += wa2*bf2f((unsigned short)(uA2>>16));
        a0 += wa3*bf2f((unsigned short)uA3); a1 += wa3*bf2f((unsigned short)(uA3>>16));
        b0 += wb0*bf2f((unsigned short)uB0); b1 += wb0*bf2f((unsigned short)(uB0>>16));
        b0 += wb1*bf2f((unsigned short)uB1); b1 += wb1*bf2f((unsigned short)(uB1>>16));
        b0 += wb2*bf2f((unsigned short)uB2); b1 += wb2*bf2f((unsigned short)(uB2>>16));
        b0 += wb3*bf2f((unsigned short)uB3); b1 += wb3*bf2f((unsigned short)(uB3>>16));
      }
    }
    int kA = k, kB = k;
    for (; kA < limA; ++kA) {
      int col = __shfl(cc, kA);
      float w_ = __shfl(wt, kA);
      if (act){
        unsigned int u = reinterpret_cast<const unsigned int*>(xt + (size_t)col*100)[lane];
        a0 += w_*bf2f((unsigned short)u);
        a1 += w_*bf2f((unsigned short)(u>>16));
      }
    }
    for (; kB < limB; ++kB) {
      int col = __shfl(cc, 32+kB);
      float w_ = __shfl(wt, 32+kB);
      if (act){
        unsigned int u = reinterpret_cast<const unsigned int*>(xt + (size_t)col*100)[lane];
        b0 += w_*bf2f((unsigned short)u);
        b1 += w_*bf2f((unsigned short)(u>>16));
      }
    }
  }
  if (act){
    float2* dstA = reinterpret_cast<float2*>(sup + (size_t)rowA*100);
    dstA[lane] = make_float2(a0, a1);
    if (hasB){
      float2* dstB = reinterpret_cast<float2*>(sup + (size_t)rowB*100);
      dstB[lane] = make_float2(b0, b1);
    }
  }
}

// ===================== gather agg D=64: half-split, one row per 32-lane half =====================
__global__ __launch_bounds__(256) void k_agg64(
    const unsigned short* __restrict__ xt, const int* __restrict__ row_start,
    const int* __restrict__ counts, const uint2* __restrict__ meta,
    float* __restrict__ sup, int N)
{
  int wv = threadIdx.x >> 6;
  int lane = threadIdx.x & 63;
  int pair = blockIdx.x*4 + wv;
  int rowA = pair*2;
  if (rowA >= N) return;
  int rowB = rowA + 1;
  bool hasB = rowB < N;
  int half = lane >> 5, sl = lane & 31;
  int myRow = half ? rowB : rowA;
  bool live = (half == 0) || hasB;
  int myStart = 0, myCnt = 0;
  if (live){ myStart = row_start[myRow]; myCnt = counts[myRow]; }
  float a0 = 0.f, a1 = 0.f;

  for (int j = 0; j < myCnt; j += 32) {
    int cc = 0; float wt = 0.f;
    if (j + sl < myCnt){ uint2 m = meta[myStart + j + sl]; cc = (int)m.x; wt = __uint_as_float(m.y); }
    int lim = min(32, myCnt - j);
    int hb = half*32;
    int k = 0;
    for (; k + 8 <= lim; k += 8) {
      const unsigned int *p0,*p1,*p2,*p3,*p4,*p5,*p6,*p7;
      float w0,w1,w2,w3,w4,w5,w6,w7;
      p0 = reinterpret_cast<const unsigned int*>(xt + (size_t)__shfl(cc,hb+k+0)*64); w0 = __shfl(wt,hb+k+0);
      p1 = reinterpret_cast<const unsigned int*>(xt + (size_t)__shfl(cc,hb+k+1)*64); w1 = __shfl(wt,hb+k+1);
      p2 = reinterpret_cast<const unsigned int*>(xt + (size_t)__shfl(cc,hb+k+2)*64); w2 = __shfl(wt,hb+k+2);
      p3 = reinterpret_cast<const unsigned int*>(xt + (size_t)__shfl(cc,hb+k+3)*64); w3 = __shfl(wt,hb+k+3);
      p4 = reinterpret_cast<const unsigned int*>(xt + (size_t)__shfl(cc,hb+k+4)*64); w4 = __shfl(wt,hb+k+4);
      p5 = reinterpret_cast<const unsigned int*>(xt + (size_t)__shfl(cc,hb+k+5)*64); w5 = __shfl(wt,hb+k+5);
      p6 = reinterpret_cast<const unsigned int*>(xt + (size_t)__shfl(cc,hb+k+6)*64); w6 = __shfl(wt,hb+k+6);
      p7 = reinterpret_cast<const unsigned int*>(xt + (size_t)__shfl(cc,hb+k+7)*64); w7 = __shfl(wt,hb+k+7);
      unsigned int u0=p0[sl],u1=p1[sl],u2=p2[sl],u3=p3[sl];
      unsigned int u4=p4[sl],u5=p5[sl],u6=p6[sl],u7=p7[sl];
      a0 += w0*bf2f((unsigned short)u0); a1 += w0*bf2f((unsigned short)(u0>>16));
      a0 += w1*bf2f((unsigned short)u1); a1 += w1*bf2f((unsigned short)(u1>>16));
      a0 += w2*bf2f((unsigned short)u2); a1 += w2*bf2f((unsigned short)(u2>>16));
      a0 += w3*bf2f((unsigned short)u3); a1 += w3*bf2f((unsigned short)(u3>>16));
      a0 += w4*bf2f((unsigned short)u4); a1 += w4*bf2f((unsigned short)(u4>>16));
      a0 += w5*bf2f((unsigned short)u5); a1 += w5*bf2f((unsigned short)(u5>>16));
      a0 += w6*bf2f((unsigned short)u6); a1 += w6*bf2f((unsigned short)(u6>>16));
      a0 += w7*bf2f((unsigned short)u7); a1 += w7*bf2f((unsigned short)(u7>>16));
    }
    for (; k < lim; ++k) {
      int col = __shfl(cc, hb+k);
      float w_ = __shfl(wt, hb+k);
      unsigned int u = reinterpret_cast<const unsigned int*>(xt + (size_t)col*64)[sl];
      a0 += w_*bf2f((unsigned short)u);
      a1 += w_*bf2f((unsigned short)(u>>16));
    }
  }
  if (live){
    float2* dst = reinterpret_cast<float2*>(sup + (size_t)myRow*64);
    dst[sl] = make_float2(a0, a1);
  }
}

// --- fused: proj(expmap0(support1)) -> hyp_act -> mobius_matvec(w2) -> +bias2 -> proj -> logmap0 ---
__global__ __launch_bounds__(256) void k_layer2(
    const float* __restrict__ sup, const float* __restrict__ w2,
    const float* __restrict__ hb2, const float* __restrict__ scal,
    unsigned short* __restrict__ xtan2, int N)
{
  __shared__ alignas(16) float w2s[64][100];
  __shared__ float xts[32][105];
  __shared__ float hbs[64];
  int tid = threadIdx.x;
  for (int i = tid; i < 1600; i += 256)
    reinterpret_cast<float4*>(&w2s[0][0])[i] = reinterpret_cast<const float4*>(w2)[i];
  if (tid < 64) hbs[tid] = hb2[tid];
  float b2sq = scal[1];
  __syncthreads();
  int rr = tid >> 3, g = tid & 7;
  int grow = blockIdx.x*32 + rr;
  bool valid = grow < N;
  float sv[13]; float sn2 = 0.f;
  #pragma unroll
  for (int m=0;m<13;m++){
    int j = g + 8*m;
    float v = (valid && j < 100) ? sup[(size_t)grow*100 + j] : 0.f;
    sv[m] = v; sn2 += v*v;
  }
  sn2 = grp8(sn2);
  float snn = fmaxf(sqrtf(sn2), MINN);
  float e1 = tanhf(snn)/snn;
  float pnA = fmaxf(tanhf(snn), MINN);
  float t1 = pnA > MAXN ? MAXN/pnA : 1.f;
  float phi = e1*t1;
  float hn = fmaxf(phi*snn, MINN);
  float lam = artanhf_(hn)/hn;
  float xn2 = 0.f;
  #pragma unroll
  for (int m=0;m<13;m++){
    int j = g + 8*m;
    if (j < 100){ float v = fmaxf(lam*phi*sv[m], 0.f); xts[rr][j] = v; xn2 += v*v; }
  }
  xn2 = grp8(xn2);
  float xn = fmaxf(sqrtf(xn2), MINN);
  float e2 = tanhf(xn)/xn;
  float pnB = fmaxf(tanhf(xn), MINN);
  float t2 = pnB > MAXN ? MAXN/pnB : 1.f;
  float psi = e2*t2;
  __syncthreads();
  float z[8] = {};
  for (int j=0;j<100;j++){
    float xv = xts[rr][j];
    #pragma unroll
    for (int m=0;m<8;m++) z[m] += xv * w2s[g+8*m][j];
  }
  float zn2 = 0.f, dz = 0.f;
  #pragma unroll
  for (int m=0;m<8;m++){ zn2 += z[m]*z[m]; dz += z[m]*hbs[g+8*m]; }
  zn2 = grp8(zn2); dz = grp8(dz);
  float xnh = fmaxf(psi*xn, MINN);
  float zn = sqrtf(zn2);
  float mxn = fmaxf(psi*zn, MINN);
  float rs = tanhf(mxn/xnh*artanhf_(xnh))/mxn;
  if (zn2 == 0.f) rs = 0.f;
  float rn = rs*psi*zn;
  float t3 = rn > MAXN ? MAXN/fmaxf(rn,MINN) : 1.f;
  float alpha = t3*rs*psi;
  float x2 = alpha*alpha*zn2;
  float xy = alpha*dz;
  float den = fmaxf(1.f + 2.f*xy + x2*b2sq, MINN);
  float A = (1.f + 2.f*xy + b2sq)/den, B = (1.f - x2)/den;
  float Aa = A*alpha;
  float ov[8]; float on2 = 0.f;
  #pragma unroll
  for (int m=0;m<8;m++){ ov[m] = Aa*z[m] + B*hbs[g+8*m]; on2 += ov[m]*ov[m]; }
  on2 = grp8(on2);
  float on = sqrtf(on2);
  float onc = fmaxf(on, MINN);
  float t4 = onc > MAXN ? MAXN/onc : 1.f;
  float pn4 = fmaxf(t4*on, MINN);
  float fs = artanhf_(pn4)/pn4 * t4;
  if (valid)
    #pragma unroll
    for (int m=0;m<8;m++) xtan2[(size_t)grow*64 + g + 8*m] = f2bf(fs*ov[m]);
}

// --- fused: proj(expmap0(support2)) -> hyp_act -> logmap0 -> linear(7) + relu -> log_softmax ---
__global__ __launch_bounds__(256) void k_decode(
    const float* __restrict__ sup2, const float* __restrict__ lw,
    const float* __restrict__ lb, float* __restrict__ out, int N)
{
  __shared__ float lws[7][64];
  __shared__ float lbs[7];
  int tid = threadIdx.x;
  for (int i = tid; i < 448; i += 256) lws[i>>6][i&63] = lw[i];
  if (tid < 7) lbs[tid] = lb[tid];
  __syncthreads();
  int rr = tid >> 3, g = tid & 7;
  int grow = blockIdx.x*32 + rr;
  bool valid = grow < N;
  float sv[8]; float sn2 = 0.f;
  #pragma unroll
  for (int m=0;m<8;m++){
    int j = g + 8*m;
    float v = valid ? sup2[(size_t)grow*64 + j] : 0.f;
    sv[m] = v; sn2 += v*v;
  }
  sn2 = grp8(sn2);
  float snn = fmaxf(sqrtf(sn2), MINN);
  float e1 = tanhf(snn)/snn;
  float pnA = fmaxf(tanhf(snn), MINN);
  float t1 = pnA > MAXN ? MAXN/pnA : 1.f;
  float phi = e1*t1;
  float hn = fmaxf(phi*snn, MINN);
  float lam = artanhf_(hn)/hn;
  float xt[8]; float xn2 = 0.f;
  #pragma unroll
  for (int m=0;m<8;m++){ xt[m] = fmaxf(lam*phi*sv[m], 0.f); xn2 += xt[m]*xt[m]; }
  xn2 = grp8(xn2);
  float xn = fmaxf(sqrtf(xn2), MINN);
  float e2 = tanhf(xn)/xn;
  float pnB = fmaxf(tanhf(xn), MINN);
  float t2 = pnB > MAXN ? MAXN/pnB : 1.f;
  float psi = e2*t2;
  float tn = fmaxf(psi*xn, MINN);
  float lam2 = artanhf_(tn)/tn;
  float tc = lam2*psi;
  float lg[7];
  #pragma unroll
  for (int k=0;k<7;k++){
    float p = 0.f;
    #pragma unroll
    for (int m=0;m<8;m++) p += xt[m]*lws[k][g+8*m];
    p = grp8(p) * tc;
    lg[k] = fmaxf(p + lbs[k], 0.f);
  }
  float mx = lg[0];
  #pragma unroll
  for (int k=1;k<7;k++) mx = fmaxf(mx, lg[k]);
  float se = 0.f;
  #pragma unroll
  for (int k=0;k<7;k++) se += expf(lg[k]-mx);
  float lse = logf(se);
  if (valid && g < 7) out[(size_t)grow*7 + g] = lg[g] - mx - lse;
}

extern "C" void kernel_launch(void* const* d_in, const int* in_sizes, int n_in,
                              void* d_out, int out_size, void* d_ws, size_t ws_size,
                              hipStream_t stream)
{
  const float* x  = (const float*)d_in[0];
  const int*   er = (const int*)  d_in[1];
  const int*   ec = (const int*)  d_in[2];
  const float* ew = (const float*)d_in[3];
  const float* w1 = (const float*)d_in[4];
  const float* b1 = (const float*)d_in[5];
  const float* w2 = (const float*)d_in[6];
  const float* b2 = (const float*)d_in[7];
  const float* lw = (const float*)d_in[8];
  const float* lb = (const float*)d_in[9];
  float* out = (float*)d_out;
  int N = in_sizes[0] / 1433;
  int E = in_sizes[1];

  float* W = (float*)d_ws;
  float* hb1  = W;                                      // 128
  float* hb2  = W + 128;                                // 64
  float* scal = W + 192;                                // 2
  unsigned short* w1hi = (unsigned short*)(W + 256);    // 112*KPAD ushorts = 82432 floats
  uint2* meta = (uint2*)(W + 82688);                    // E * 8B
  int*   counts    = (int*)(W + 82688 + 2*(size_t)E);   // N
  int*   row_start = counts + N;                        // N
  int*   cursor    = row_start + N;                     // N
  int*   blksum    = cursor + N;                        // 128
  unsigned short* xtanb = (unsigned short*)(blksum + 128);  // N*100 ushorts (xtan1 / xtan2)
  float* sup = (float*)(xtanb + (size_t)N*100);         // N*100 floats (sup1 / sup2)

  int nblk_scan = (N + 1023) / 1024;
  int nb128 = (N + 127)/128;
  int npair = (N + 1)/2;
  int nbg = (npair + 3)/4;
  int nb32 = (N + 31)/32;

  k_prep<<<(112*KPAD + 255)/256, 256, 0, stream>>>(w1, b1, b2, w1hi, hb1, hb2, scal, counts, N);
  k_lin1_mfma<<<nb128, 512, 0, stream>>>(x, w1hi, hb1, scal, xtanb, N, er, counts, E);
  k_scan1<<<nblk_scan, 256, 0, stream>>>(counts, row_start, blksum, N);
  k_scan3<<<(N + 255)/256, 256, 0, stream>>>(row_start, blksum, cursor, N);
  k_scatter<<<(E + 255)/256, 256, 0, stream>>>(er, ec, ew, cursor, meta, E);
  k_agg100<<<nbg, 256, 0, stream>>>(xtanb, row_start, counts, meta, sup, N);
  k_layer2<<<nb32, 256, 0, stream>>>(sup, w2, hb2, scal, xtanb, N);
  k_agg64<<<nbg, 256, 0, stream>>>(xtanb, row_start, counts, meta, sup, N);
  k_decode<<<nb32, 256, 0, stream>>>(sup, lw, lb, out, N);
}

// Round 19
// 546.276 us; speedup vs baseline: 1.9883x; 1.0306x over previous
//
#include <hip/hip_runtime.h>
#include <hip/hip_bf16.h>
#include <math.h>

#define MINN 1e-15f
#define MAXN 0.996f  // (1 - 4e-3)/sqrt(c), c=1

#define KPAD 1472    // 23 * 64

typedef __attribute__((ext_vector_type(8))) short short8;
typedef __attribute__((ext_vector_type(4))) float f32x4;

__device__ __forceinline__ float artanhf_(float v){
  v = fminf(fmaxf(v, -0.9999999f), 0.9999999f);
  return 0.5f*(log1pf(v) - log1pf(-v));
}
__device__ __forceinline__ float grp8(float v){
  v += __shfl_xor(v,1,8); v += __shfl_xor(v,2,8); v += __shfl_xor(v,4,8); return v;
}
__device__ __forceinline__ float grp16w(float v){
  v += __shfl_xor(v,1,16); v += __shfl_xor(v,2,16);
  v += __shfl_xor(v,4,16); v += __shfl_xor(v,8,16); return v;
}
__device__ __forceinline__ unsigned short f2bf(float f){
  unsigned int u = __float_as_uint(f);
  unsigned int r = (u + 0x7fffu + ((u >> 16) & 1u)) >> 16;  // RNE
  return (unsigned short)r;
}
__device__ __forceinline__ float bf2f(unsigned short h){
  return __uint_as_float(((unsigned int)h) << 16);
}
__device__ __forceinline__ unsigned short f2bf_c(float f){
  __hip_bfloat16 b = __float2bfloat16(f);
  return *reinterpret_cast<unsigned short*>(&b);
}

typedef __attribute__((address_space(1))) const unsigned int gu32;
typedef __attribute__((address_space(3))) unsigned int su32;
__device__ __forceinline__ void gload_lds16(const void* g, void* s){
  __builtin_amdgcn_global_load_lds((gu32*)g, (su32*)s, 16, 0, 0);
}

// --- fused prep: w1 -> bf16 hi (RNE), counts zeroing, bias (block 0) ---
__global__ __launch_bounds__(256) void k_prep(const float* __restrict__ w1,
    const float* __restrict__ b1, const float* __restrict__ b2,
    unsigned short* __restrict__ w1hi,
    float* __restrict__ hb1, float* __restrict__ hb2, float* __restrict__ scal,
    int* __restrict__ counts, int N){
  int idx = blockIdx.x*256 + threadIdx.x;
  if (idx < 112*KPAD){
    int col = idx / KPAD, k = idx - col*KPAD;
    float v = (col < 100 && k < 1433) ? w1[(size_t)col*1433 + k] : 0.f;
    w1hi[idx] = f2bf(v);
  }
  if (idx < N) counts[idx] = 0;

  if (blockIdx.x == 0){
    __shared__ float red[128];
    int t = threadIdx.x;
    float v = (t < 100) ? b1[t] : 0.f;
    if (t < 128) red[t] = v*v;
    __syncthreads();
    for (int s=64;s;s>>=1){ if (t<s) red[t]+=red[t+s]; __syncthreads(); }
    float n2 = red[0]; __syncthreads();
    float n = fmaxf(sqrtf(n2), MINN);
    float s1 = tanhf(n)/n;
    float pn = fmaxf(tanhf(n), MINN);
    float t1 = pn > MAXN ? MAXN/pn : 1.f;
    float hv = s1*t1*v;
    if (t < 128) hb1[t] = (t<100) ? hv : 0.f;
    if (t < 128) red[t] = (t<100) ? hv*hv : 0.f;
    __syncthreads();
    for (int s=64;s;s>>=1){ if (t<s) red[t]+=red[t+s]; __syncthreads(); }
    if (t==0) scal[0] = red[0];
    __syncthreads();
    float v2 = (t < 64) ? b2[t] : 0.f;
    if (t < 128) red[t] = v2*v2;
    __syncthreads();
    for (int s=64;s;s>>=1){ if (t<s) red[t]+=red[t+s]; __syncthreads(); }
    float n2b = red[0]; __syncthreads();
    float nb = fmaxf(sqrtf(n2b), MINN);
    float s1b = tanhf(nb)/nb;
    float pnb = fmaxf(tanhf(nb), MINN);
    float t1b = pnb > MAXN ? MAXN/pnb : 1.f;
    float hvb = s1b*t1b*v2;
    if (t < 64) hb2[t] = hvb;
    if (t < 128) red[t] = (t<64) ? hvb*hvb : 0.f;
    __syncthreads();
    for (int s=64;s;s>>=1){ if (t<s) red[t]+=red[t+s]; __syncthreads(); }
    if (t==0) scal[1] = red[0];
  }
}

// --- MFMA lin1 + edge histogram. x split (hi+lo bf16), w plain bf16 (2 MFMA/tile).
// 64 rows/block, 4 waves x 16 rows, BK=64, 256 threads, LDS 28KB.
// Same inner loop as the 560µs best; smaller blocks = 4 independent barrier
// domains per CU (was 2) so per-k-step vmcnt(0)+barrier drains stall 1/4 of
// the CU's waves instead of 1/2. VGPR ~68 natural (r17: never pin below need).
__global__ __launch_bounds__(256) void k_lin1_mfma(
    const float* __restrict__ x, const unsigned short* __restrict__ w1hi,
    const float* __restrict__ hb1,
    const float* __restrict__ scal, unsigned short* __restrict__ xtan1, int N,
    const int* __restrict__ er, int* __restrict__ counts, int E)
{
  __shared__ alignas(16) char bsm[2*14*1024];   // 28 KB
  int tid = threadIdx.x;

  // --- edge histogram (overlaps with staging/memory stalls) ---
  {
    int gsz = gridDim.x * 256;
    for (int e = blockIdx.x*256 + tid; e < E; e += gsz)
      atomicAdd(&counts[er[e]], 1);
  }

  int w = tid >> 6, l = tid & 63;               // 4 waves
  int lr = l & 15, lg = l >> 4;
  int bm = blockIdx.x * 64;
  int row0 = bm + w*16;
  int r = row0 + lr;
  const float* xr = x + (size_t)min(r, N-1)*1433 + lg*8;
  float b1sq = scal[0];

  f32x4 acc[7];
  #pragma unroll
  for (int t=0;t<7;t++) acc[t] = (f32x4){0.f,0.f,0.f,0.f};
  float sq = 0.f;

  // chunk cc in [0,14): h = cc>=7 (k-half), t = cc-7h (col-tile).
  // lane l holds B[t*16+(l&15)][kbase + h*32 + (l>>4)*8 .. +8] at (buf*14+cc)*1024 + l*16.
  auto stage = [&](int buf, int kbase){
    #pragma unroll
    for (int c = 0; c < 4; ++c){
      int cc = w + 4*c;                          // 0..15 across 4 waves
      if (cc < 14){
        int h = (cc >= 7) ? 1 : 0;
        int t = cc - h*7;
        const unsigned short* src = w1hi + (size_t)(t*16 + lr)*KPAD + kbase + h*32 + lg*8;
        gload_lds16(src, bsm + (buf*14 + cc)*1024);
      }
    }
  };
  auto xload = [&](float* d, int kbase){
    #pragma unroll
    for (int h = 0; h < 2; ++h){
      int kk = kbase + h*32;
      const float* p = xr + kk;
      if (kk + 32 <= 1433) {
        #pragma unroll
        for (int j=0;j<8;j++) d[h*8+j] = p[j];
      } else {
        #pragma unroll
        for (int j=0;j<8;j++){
          bool kv = (kk + lg*8 + j) < 1433;
          d[h*8+j] = kv ? p[j] : 0.f;
        }
      }
    }
  };

  float xa[16];
  xload(xa, 0);
  stage(0, 0);
  __syncthreads();

  for (int kb = 0; kb < 23; ++kb) {
    int cur = kb & 1, nxt = cur ^ 1;
    int nk = (kb + 1) * 64;

    float xb[16];
    if (kb + 1 < 23){
      xload(xb, nk);      // long-latency x prefetch issued first
      stage(nxt, nk);
    } else {
      #pragma unroll
      for (int j=0;j<16;j++) xb[j] = 0.f;
    }

    #pragma unroll
    for (int h = 0; h < 2; ++h){
      short8 ah, al;
      #pragma unroll
      for (int j=0;j<8;j++){
        float v = xa[h*8+j];
        sq = fmaf(v, v, sq);
        unsigned short hu = f2bf_c(v);
        ah[j] = (short)hu;
        float hf = bf2f(hu);
        al[j] = (short)f2bf_c(v - hf);
      }
      const char* base = bsm + (cur*14 + h*7)*1024 + (l << 4);
      short8 bh[7];
      #pragma unroll
      for (int t=0;t<7;t++)
        bh[t] = *reinterpret_cast<const short8*>(base + t*1024);
      #pragma unroll
      for (int t=0;t<7;t++){
        acc[t] = __builtin_amdgcn_mfma_f32_16x16x32_bf16(ah, bh[t], acc[t], 0,0,0);
        acc[t] = __builtin_amdgcn_mfma_f32_16x16x32_bf16(al, bh[t], acc[t], 0,0,0);
      }
    }
    #pragma unroll
    for (int j=0;j<16;j++) xa[j] = xb[j];

    __syncthreads();
  }

  sq += __shfl_xor(sq, 16); sq += __shfl_xor(sq, 32);

  float hbv[7];
  #pragma unroll
  for (int t=0;t<7;t++) hbv[t] = hb1[t*16 + lr];

  #pragma unroll
  for (int r4=0;r4<4;r4++){
    int rrow = 4*lg + r4;
    float v[7];
    #pragma unroll
    for (int t=0;t<7;t++) v[t] = acc[t][r4];
    float yn2 = 0.f, dotb = 0.f;
    #pragma unroll
    for (int t=0;t<7;t++){ yn2 += v[t]*v[t]; dotb += v[t]*hbv[t]; }
    yn2 = grp16w(yn2); dotb = grp16w(dotb);
    float xn2 = __shfl(sq, rrow);

    float un = fmaxf(sqrtf(xn2), MINN);
    float th = tanhf(un);
    float sE = th/un;
    float pn = fmaxf(th, MINN);
    float t1 = pn > MAXN ? MAXN/pn : 1.f;
    float gam = sE*t1;
    float xh = fmaxf(gam*un, MINN);
    float yn = sqrtf(yn2);
    float mxn = fmaxf(gam*yn, MINN);
    float rs = tanhf(mxn/xh*artanhf_(xh))/mxn;
    if (yn2 == 0.f) rs = 0.f;
    float rn = rs*gam*yn;
    float t2 = rn > MAXN ? MAXN/fmaxf(rn,MINN) : 1.f;
    float alpha = t2*rs*gam;
    float x2v = alpha*alpha*yn2;
    float xyv = alpha*dotb;
    float den = fmaxf(1.f + 2.f*xyv + x2v*b1sq, MINN);
    float A = (1.f + 2.f*xyv + b1sq)/den, B = (1.f - x2v)/den;
    float Aa = A*alpha;
    float on2 = 0.f;
    float o[7];
    #pragma unroll
    for (int t=0;t<7;t++){ o[t] = Aa*v[t] + B*hbv[t]; on2 += o[t]*o[t]; }
    on2 = grp16w(on2);
    float on = sqrtf(on2);
    float onc = fmaxf(on, MINN);
    float t3 = onc > MAXN ? MAXN/onc : 1.f;
    float pn3 = fmaxf(t3*on, MINN);
    float fs = artanhf_(pn3)/pn3 * t3;

    int grow = row0 + rrow;
    if (grow < N){
      #pragma unroll
      for (int t=0;t<7;t++){
        int c = t*16 + lr;
        if (c < 100) xtan1[(size_t)grow*100 + c] = f2bf(fs*o[t]);
      }
    }
  }
}

// ===================== CSR build (scan + scatter) =====================
__global__ __launch_bounds__(256) void k_scan1(const int* __restrict__ counts, int* __restrict__ row_start,
                                               int* __restrict__ blksum, int N){
  __shared__ int s[256];
  int t = threadIdx.x;
  int base = blockIdx.x*1024 + t*4;
  int v[4]; int sum = 0;
  #pragma unroll
  for (int i=0;i<4;i++){ v[i] = (base+i < N) ? counts[base+i] : 0; sum += v[i]; }
  s[t] = sum; __syncthreads();
  for (int off=1; off<256; off<<=1){
    int val = (t >= off) ? s[t-off] : 0;
    __syncthreads();
    s[t] += val;
    __syncthreads();
  }
  int run = (t > 0) ? s[t-1] : 0;
  #pragma unroll
  for (int i=0;i<4;i++){ if (base+i < N) row_start[base+i] = run; run += v[i]; }
  if (t == 255) blksum[blockIdx.x] = s[255];
}

__global__ __launch_bounds__(256) void k_scan3(int* __restrict__ row_start, const int* __restrict__ blksum,
                                               int* __restrict__ cursor, int N){
  __shared__ int pref;
  if (threadIdx.x == 0){
    int seg = blockIdx.x >> 2;
    int s = 0;
    for (int q = 0; q < seg; ++q) s += blksum[q];
    pref = s;
  }
  __syncthreads();
  int i = blockIdx.x*256 + threadIdx.x;
  if (i < N){ int v = row_start[i] + pref; row_start[i] = v; cursor[i] = v; }
}

__global__ __launch_bounds__(256) void k_scatter(const int* __restrict__ er, const int* __restrict__ ec,
    const float* __restrict__ ew, int* __restrict__ cursor,
    uint2* __restrict__ meta, int E){
  int e = blockIdx.x*256 + threadIdx.x;
  if (e < E){
    int r = er[e];
    int pos = atomicAdd(&cursor[r], 1);
    uint2 m;
    m.x = (unsigned int)ec[e];
    m.y = __float_as_uint(ew[e]);
    meta[pos] = m;
  }
}

// ===================== gather agg D=100: TWO rows per wave =====================
__global__ __launch_bounds__(256) void k_agg100(
    const unsigned short* __restrict__ xt, const int* __restrict__ row_start,
    const int* __restrict__ counts, const uint2* __restrict__ meta,
    float* __restrict__ sup, int N)
{
  int wv = threadIdx.x >> 6;
  int lane = threadIdx.x & 63;
  int pair = blockIdx.x*4 + wv;
  int rowA = pair*2;
  if (rowA >= N) return;
  int rowB = rowA + 1;
  bool hasB = rowB < N;
  int sl = lane & 31, half = lane >> 5;
  int startA = row_start[rowA], cntA = counts[rowA];
  int startB = hasB ? row_start[rowB] : 0;
  int cntB   = hasB ? counts[rowB] : 0;
  bool act = lane < 50;
  float a0=0.f, a1=0.f, b0=0.f, b1=0.f;
  int cmax = max(cntA, cntB);

  for (int j = 0; j < cmax; j += 32) {
    int cc = 0; float wt = 0.f;
    int myStart = half ? startB : startA;
    int myCnt   = half ? cntB   : cntA;
    if (j + sl < myCnt){ uint2 m = meta[myStart + j + sl]; cc = (int)m.x; wt = __uint_as_float(m.y); }
    int limA = min(32, cntA - j);
    int limB = min(32, cntB - j);
    int limJ = min(limA, limB);
    int k = 0;
    for (; k + 4 <= limJ; k += 4) {
      const unsigned int *pa0,*pa1,*pa2,*pa3,*pb0,*pb1,*pb2,*pb3;
      float wa0,wa1,wa2,wa3,wb0,wb1,wb2,wb3;
      pa0 = reinterpret_cast<const unsigned int*>(xt + (size_t)__shfl(cc,k+0)*100); wa0 = __shfl(wt,k+0);
      pa1 = reinterpret_cast<const unsigned int*>(xt + (size_t)__shfl(cc,k+1)*100); wa1 = __shfl(wt,k+1);
      pa2 = reinterpret_cast<const unsigned int*>(xt + (size_t)__shfl(cc,k+2)*100); wa2 = __shfl(wt,k+2);
      pa3 = reinterpret_cast<const unsigned int*>(xt + (size_t)__shfl(cc,k+3)*100); wa3 = __shfl(wt,k+3);
      pb0 = reinterpret_cast<const unsigned int*>(xt + (size_t)__shfl(cc,32+k+0)*100); wb0 = __shfl(wt,32+k+0);
      pb1 = reinterpret_cast<const unsigned int*>(xt + (size_t)__shfl(cc,32+k+1)*100); wb1 = __shfl(wt,32+k+1);
      pb2 = reinterpret_cast<const unsigned int*>(xt + (size_t)__shfl(cc,32+k+2)*100); wb2 = __shfl(wt,32+k+2);
      pb3 = reinterpret_cast<const unsigned int*>(xt + (size_t)__shfl(cc,32+k+3)*100); wb3 = __shfl(wt,32+k+3);
      if (act){
        unsigned int uA0=pa0[lane],uA1=pa1[lane],uA2=pa2[lane],uA3=pa3[lane];
        unsigned int uB0=pb0[lane],uB1=pb1[lane],uB2=pb2[lane],uB3=pb3[lane];
        a0 += wa0*bf2f((unsigned short)uA0); a1 += wa0*bf2f((unsigned short)(uA0>>16));
        a0 += wa1*bf2f((unsigned short)uA1); a1 += wa1*bf2f((unsigned short)(uA1>>16));
        a0 += wa2*bf2f((unsigned short)uA2); a1 += wa2*bf2f((unsigned short)(uA2>>16));
        a0 += wa3*bf2f((unsigned short)uA3); a1 += wa3*bf2f((unsigned short)(uA3>>16));
        b0 += wb0*bf2f((unsigned short)uB0); b1 += wb0*bf2f((unsigned short)(uB0>>16));
        b0 += wb1*bf2f((unsigned short)uB1); b1 += wb1*bf2f((unsigned short)(uB1>>16));
        b0 += wb2*bf2f((unsigned short)uB2); b1 += wb2*bf2f((unsigned short)(uB2>>16));
        b0 += wb3*bf2f((unsigned short)uB3); b1 += wb3*bf2f((unsigned short)(uB3>>16));
      }
    }
    int kA = k, kB = k;
    for (; kA < limA; ++kA) {
      int col = __shfl(cc, kA);
      float w_ = __shfl(wt, kA);
      if (act){
        unsigned int u = reinterpret_cast<const unsigned int*>(xt + (size_t)col*100)[lane];
        a0 += w_*bf2f((unsigned short)u);
        a1 += w_*bf2f((unsigned short)(u>>16));
      }
    }
    for (; kB < limB; ++kB) {
      int col = __shfl(cc, 32+kB);
      float w_ = __shfl(wt, 32+kB);
      if (act){
        unsigned int u = reinterpret_cast<const unsigned int*>(xt + (size_t)col*100)[lane];
        b0 += w_*bf2f((unsigned short)u);
        b1 += w_*bf2f((unsigned short)(u>>16));
      }
    }
  }
  if (act){
    float2* dstA = reinterpret_cast<float2*>(sup + (size_t)rowA*100);
    dstA[lane] = make_float2(a0, a1);
    if (hasB){
      float2* dstB = reinterpret_cast<float2*>(sup + (size_t)rowB*100);
      dstB[lane] = make_float2(b0, b1);
    }
  }
}

// ===================== gather agg D=64: half-split, one row per 32-lane half =====================
__global__ __launch_bounds__(256) void k_agg64(
    const unsigned short* __restrict__ xt, const int* __restrict__ row_start,
    const int* __restrict__ counts, const uint2* __restrict__ meta,
    float* __restrict__ sup, int N)
{
  int wv = threadIdx.x >> 6;
  int lane = threadIdx.x & 63;
  int pair = blockIdx.x*4 + wv;
  int rowA = pair*2;
  if (rowA >= N) return;
  int rowB = rowA + 1;
  bool hasB = rowB < N;
  int half = lane >> 5, sl = lane & 31;
  int myRow = half ? rowB : rowA;
  bool live = (half == 0) || hasB;
  int myStart = 0, myCnt = 0;
  if (live){ myStart = row_start[myRow]; myCnt = counts[myRow]; }
  float a0 = 0.f, a1 = 0.f;

  for (int j = 0; j < myCnt; j += 32) {
    int cc = 0; float wt = 0.f;
    if (j + sl < myCnt){ uint2 m = meta[myStart + j + sl]; cc = (int)m.x; wt = __uint_as_float(m.y); }
    int lim = min(32, myCnt - j);
    int hb = half*32;
    int k = 0;
    for (; k + 8 <= lim; k += 8) {
      const unsigned int *p0,*p1,*p2,*p3,*p4,*p5,*p6,*p7;
      float w0,w1,w2,w3,w4,w5,w6,w7;
      p0 = reinterpret_cast<const unsigned int*>(xt + (size_t)__shfl(cc,hb+k+0)*64); w0 = __shfl(wt,hb+k+0);
      p1 = reinterpret_cast<const unsigned int*>(xt + (size_t)__shfl(cc,hb+k+1)*64); w1 = __shfl(wt,hb+k+1);
      p2 = reinterpret_cast<const unsigned int*>(xt + (size_t)__shfl(cc,hb+k+2)*64); w2 = __shfl(wt,hb+k+2);
      p3 = reinterpret_cast<const unsigned int*>(xt + (size_t)__shfl(cc,hb+k+3)*64); w3 = __shfl(wt,hb+k+3);
      p4 = reinterpret_cast<const unsigned int*>(xt + (size_t)__shfl(cc,hb+k+4)*64); w4 = __shfl(wt,hb+k+4);
      p5 = reinterpret_cast<const unsigned int*>(xt + (size_t)__shfl(cc,hb+k+5)*64); w5 = __shfl(wt,hb+k+5);
      p6 = reinterpret_cast<const unsigned int*>(xt + (size_t)__shfl(cc,hb+k+6)*64); w6 = __shfl(wt,hb+k+6);
      p7 = reinterpret_cast<const unsigned int*>(xt + (size_t)__shfl(cc,hb+k+7)*64); w7 = __shfl(wt,hb+k+7);
      unsigned int u0=p0[sl],u1=p1[sl],u2=p2[sl],u3=p3[sl];
      unsigned int u4=p4[sl],u5=p5[sl],u6=p6[sl],u7=p7[sl];
      a0 += w0*bf2f((unsigned short)u0); a1 += w0*bf2f((unsigned short)(u0>>16));
      a0 += w1*bf2f((unsigned short)u1); a1 += w1*bf2f((unsigned short)(u1>>16));
      a0 += w2*bf2f((unsigned short)u2); a1 += w2*bf2f((unsigned short)(u2>>16));
      a0 += w3*bf2f((unsigned short)u3); a1 += w3*bf2f((unsigned short)(u3>>16));
      a0 += w4*bf2f((unsigned short)u4); a1 += w4*bf2f((unsigned short)(u4>>16));
      a0 += w5*bf2f((unsigned short)u5); a1 += w5*bf2f((unsigned short)(u5>>16));
      a0 += w6*bf2f((unsigned short)u6); a1 += w6*bf2f((unsigned short)(u6>>16));
      a0 += w7*bf2f((unsigned short)u7); a1 += w7*bf2f((unsigned short)(u7>>16));
    }
    for (; k < lim; ++k) {
      int col = __shfl(cc, hb+k);
      float w_ = __shfl(wt, hb+k);
      unsigned int u = reinterpret_cast<const unsigned int*>(xt + (size_t)col*64)[sl];
      a0 += w_*bf2f((unsigned short)u);
      a1 += w_*bf2f((unsigned short)(u>>16));
    }
  }
  if (live){
    float2* dst = reinterpret_cast<float2*>(sup + (size_t)myRow*64);
    dst[sl] = make_float2(a0, a1);
  }
}

// --- fused: proj(expmap0(support1)) -> hyp_act -> mobius_matvec(w2) -> +bias2 -> proj -> logmap0 ---
__global__ __launch_bounds__(256) void k_layer2(
    const float* __restrict__ sup, const float* __restrict__ w2,
    const float* __restrict__ hb2, const float* __restrict__ scal,
    unsigned short* __restrict__ xtan2, int N)
{
  __shared__ alignas(16) float w2s[64][100];
  __shared__ float xts[32][105];
  __shared__ float hbs[64];
  int tid = threadIdx.x;
  for (int i = tid; i < 1600; i += 256)
    reinterpret_cast<float4*>(&w2s[0][0])[i] = reinterpret_cast<const float4*>(w2)[i];
  if (tid < 64) hbs[tid] = hb2[tid];
  float b2sq = scal[1];
  __syncthreads();
  int rr = tid >> 3, g = tid & 7;
  int grow = blockIdx.x*32 + rr;
  bool valid = grow < N;
  float sv[13]; float sn2 = 0.f;
  #pragma unroll
  for (int m=0;m<13;m++){
    int j = g + 8*m;
    float v = (valid && j < 100) ? sup[(size_t)grow*100 + j] : 0.f;
    sv[m] = v; sn2 += v*v;
  }
  sn2 = grp8(sn2);
  float snn = fmaxf(sqrtf(sn2), MINN);
  float e1 = tanhf(snn)/snn;
  float pnA = fmaxf(tanhf(snn), MINN);
  float t1 = pnA > MAXN ? MAXN/pnA : 1.f;
  float phi = e1*t1;
  float hn = fmaxf(phi*snn, MINN);
  float lam = artanhf_(hn)/hn;
  float xn2 = 0.f;
  #pragma unroll
  for (int m=0;m<13;m++){
    int j = g + 8*m;
    if (j < 100){ float v = fmaxf(lam*phi*sv[m], 0.f); xts[rr][j] = v; xn2 += v*v; }
  }
  xn2 = grp8(xn2);
  float xn = fmaxf(sqrtf(xn2), MINN);
  float e2 = tanhf(xn)/xn;
  float pnB = fmaxf(tanhf(xn), MINN);
  float t2 = pnB > MAXN ? MAXN/pnB : 1.f;
  float psi = e2*t2;
  __syncthreads();
  float z[8] = {};
  for (int j=0;j<100;j++){
    float xv = xts[rr][j];
    #pragma unroll
    for (int m=0;m<8;m++) z[m] += xv * w2s[g+8*m][j];
  }
  float zn2 = 0.f, dz = 0.f;
  #pragma unroll
  for (int m=0;m<8;m++){ zn2 += z[m]*z[m]; dz += z[m]*hbs[g+8*m]; }
  zn2 = grp8(zn2); dz = grp8(dz);
  float xnh = fmaxf(psi*xn, MINN);
  float zn = sqrtf(zn2);
  float mxn = fmaxf(psi*zn, MINN);
  float rs = tanhf(mxn/xnh*artanhf_(xnh))/mxn;
  if (zn2 == 0.f) rs = 0.f;
  float rn = rs*psi*zn;
  float t3 = rn > MAXN ? MAXN/fmaxf(rn,MINN) : 1.f;
  float alpha = t3*rs*psi;
  float x2 = alpha*alpha*zn2;
  float xy = alpha*dz;
  float den = fmaxf(1.f + 2.f*xy + x2*b2sq, MINN);
  float A = (1.f + 2.f*xy + b2sq)/den, B = (1.f - x2)/den;
  float Aa = A*alpha;
  float ov[8]; float on2 = 0.f;
  #pragma unroll
  for (int m=0;m<8;m++){ ov[m] = Aa*z[m] + B*hbs[g+8*m]; on2 += ov[m]*ov[m]; }
  on2 = grp8(on2);
  float on = sqrtf(on2);
  float onc = fmaxf(on, MINN);
  float t4 = onc > MAXN ? MAXN/onc : 1.f;
  float pn4 = fmaxf(t4*on, MINN);
  float fs = artanhf_(pn4)/pn4 * t4;
  if (valid)
    #pragma unroll
    for (int m=0;m<8;m++) xtan2[(size_t)grow*64 + g + 8*m] = f2bf(fs*ov[m]);
}

// --- fused: proj(expmap0(support2)) -> hyp_act -> logmap0 -> linear(7) + relu -> log_softmax ---
__global__ __launch_bounds__(256) void k_decode(
    const float* __restrict__ sup2, const float* __restrict__ lw,
    const float* __restrict__ lb, float* __restrict__ out, int N)
{
  __shared__ float lws[7][64];
  __shared__ float lbs[7];
  int tid = threadIdx.x;
  for (int i = tid; i < 448; i += 256) lws[i>>6][i&63] = lw[i];
  if (tid < 7) lbs[tid] = lb[tid];
  __syncthreads();
  int rr = tid >> 3, g = tid & 7;
  int grow = blockIdx.x*32 + rr;
  bool valid = grow < N;
  float sv[8]; float sn2 = 0.f;
  #pragma unroll
  for (int m=0;m<8;m++){
    int j = g + 8*m;
    float v = valid ? sup2[(size_t)grow*64 + j] : 0.f;
    sv[m] = v; sn2 += v*v;
  }
  sn2 = grp8(sn2);
  float snn = fmaxf(sqrtf(sn2), MINN);
  float e1 = tanhf(snn)/snn;
  float pnA = fmaxf(tanhf(snn), MINN);
  float t1 = pnA > MAXN ? MAXN/pnA : 1.f;
  float phi = e1*t1;
  float hn = fmaxf(phi*snn, MINN);
  float lam = artanhf_(hn)/hn;
  float xt[8]; float xn2 = 0.f;
  #pragma unroll
  for (int m=0;m<8;m++){ xt[m] = fmaxf(lam*phi*sv[m], 0.f); xn2 += xt[m]*xt[m]; }
  xn2 = grp8(xn2);
  float xn = fmaxf(sqrtf(xn2), MINN);
  float e2 = tanhf(xn)/xn;
  float pnB = fmaxf(tanhf(xn), MINN);
  float t2 = pnB > MAXN ? MAXN/pnB : 1.f;
  float psi = e2*t2;
  float tn = fmaxf(psi*xn, MINN);
  float lam2 = artanhf_(tn)/tn;
  float tc = lam2*psi;
  float lg[7];
  #pragma unroll
  for (int k=0;k<7;k++){
    float p = 0.f;
    #pragma unroll
    for (int m=0;m<8;m++) p += xt[m]*lws[k][g+8*m];
    p = grp8(p) * tc;
    lg[k] = fmaxf(p + lbs[k], 0.f);
  }
  float mx = lg[0];
  #pragma unroll
  for (int k=1;k<7;k++) mx = fmaxf(mx, lg[k]);
  float se = 0.f;
  #pragma unroll
  for (int k=0;k<7;k++) se += expf(lg[k]-mx);
  float lse = logf(se);
  if (valid && g < 7) out[(size_t)grow*7 + g] = lg[g] - mx - lse;
}

extern "C" void kernel_launch(void* const* d_in, const int* in_sizes, int n_in,
                              void* d_out, int out_size, void* d_ws, size_t ws_size,
                              hipStream_t stream)
{
  const float* x  = (const float*)d_in[0];
  const int*   er = (const int*)  d_in[1];
  const int*   ec = (const int*)  d_in[2];
  const float* ew = (const float*)d_in[3];
  const float* w1 = (const float*)d_in[4];
  const float* b1 = (const float*)d_in[5];
  const float* w2 = (const float*)d_in[6];
  const float* b2 = (const float*)d_in[7];
  const float* lw = (const float*)d_in[8];
  const float* lb = (const float*)d_in[9];
  float* out = (float*)d_out;
  int N = in_sizes[0] / 1433;
  int E = in_sizes[1];

  float* W = (float*)d_ws;
  float* hb1  = W;                                      // 128
  float* hb2  = W + 128;                                // 64
  float* scal = W + 192;                                // 2
  unsigned short* w1hi = (unsigned short*)(W + 256);    // 112*KPAD ushorts = 82432 floats
  uint2* meta = (uint2*)(W + 82688);                    // E * 8B
  int*   counts    = (int*)(W + 82688 + 2*(size_t)E);   // N
  int*   row_start = counts + N;                        // N
  int*   cursor    = row_start + N;                     // N
  int*   blksum    = cursor + N;                        // 128
  unsigned short* xtanb = (unsigned short*)(blksum + 128);  // N*100 ushorts (xtan1 / xtan2)
  float* sup = (float*)(xtanb + (size_t)N*100);         // N*100 floats (sup1 / sup2)

  int nblk_scan = (N + 1023) / 1024;
  int nb64 = (N + 63)/64;
  int npair = (N + 1)/2;
  int nbg = (npair + 3)/4;
  int nb32 = (N + 31)/32;

  k_prep<<<(112*KPAD + 255)/256, 256, 0, stream>>>(w1, b1, b2, w1hi, hb1, hb2, scal, counts, N);
  k_lin1_mfma<<<nb64, 256, 0, stream>>>(x, w1hi, hb1, scal, xtanb, N, er, counts, E);
  k_scan1<<<nblk_scan, 256, 0, stream>>>(counts, row_start, blksum, N);
  k_scan3<<<(N + 255)/256, 256, 0, stream>>>(row_start, blksum, cursor, N);
  k_scatter<<<(E + 255)/256, 256, 0, stream>>>(er, ec, ew, cursor, meta, E);
  k_agg100<<<nbg, 256, 0, stream>>>(xtanb, row_start, counts, meta, sup, N);
  k_layer2<<<nb32, 256, 0, stream>>>(sup, w2, hb2, scal, xtanb, N);
  k_agg64<<<nbg, 256, 0, stream>>>(xtanb, row_start, counts, meta, sup, N);
  k_decode<<<nb32, 256, 0, stream>>>(sup, lw, lb, out, N);
}